// Round 2
// baseline (37752.048 us; speedup 1.0000x reference)
//
#include <hip/hip_runtime.h>

#define QN 8
#define KN 1024
#define DN 256
#define NROWS 32768
#define IDX_BASE 8388608
#define LOSS_OFF 8650752
#define MARGIN 8e-3f
#define CAP 2097152u

// ws layout (float offsets)
#define WS_LOSS 0
#define WS_CNORM 8
#define WS_ANORM 8200
#define WS_MIN 40968
#define WS_CHOICE 73736      // u64[32768] -> 65536 floats
#define WS_CNT 139272
#define WS_CAND 139280       // uint2[CAP] -> 4194304 floats
#define WS_RESID 4333584     // float[8388608]
#define WS_RSPLIT 12722192   // bf16[8388608] -> 4194304 floats
#define WS_CSPLIT 16916496   // bf16[2097152] -> 1048576 floats

typedef __attribute__((ext_vector_type(8))) short short8v;
typedef __attribute__((ext_vector_type(4))) float f32x4;

static __device__ __forceinline__ unsigned short f2bf(float x) {
  unsigned int u = __float_as_uint(x);
  unsigned int r = (u + 0x7fffu + ((u >> 16) & 1u)) >> 16;
  return (unsigned short)r;
}

// numpy pairwise sum-of-squares over 256 floats (validated round 1: absmax 0.0)
__device__ __forceinline__ float sum256_sq_np(const float* p) {
  float h[2];
#pragma unroll
  for (int half = 0; half < 2; ++half) {
    const float* a = p + half * 128;
    float r[8];
#pragma unroll
    for (int j = 0; j < 8; ++j) r[j] = __fmul_rn(a[j], a[j]);
    for (int i = 8; i < 128; i += 8) {
#pragma unroll
      for (int j = 0; j < 8; ++j) r[j] = __fadd_rn(r[j], __fmul_rn(a[i + j], a[i + j]));
    }
    h[half] = __fadd_rn(__fadd_rn(__fadd_rn(r[0], r[1]), __fadd_rn(r[2], r[3])),
                        __fadd_rn(__fadd_rn(r[4], r[5]), __fadd_rn(r[6], r[7])));
  }
  return __fadd_rn(h[0], h[1]);
}

// cnorm (np-exact) + zero loss accumulators
__global__ void rvq_prep_norm(const float* __restrict__ cb, float* __restrict__ ws) {
  int g = blockIdx.x * blockDim.x + threadIdx.x;
  if (g < 8) ws[WS_LOSS + g] = 0.f;
  if (g < QN * KN) ws[WS_CNORM + g] = sum256_sq_np(cb + (size_t)g * DN);
}

// codebook -> bf16 (coalesced)
__global__ void rvq_prep_cast(const float* __restrict__ cb, unsigned short* __restrict__ cs) {
  int gid = blockIdx.x * blockDim.x + threadIdx.x;   // 131072 threads
  const float4* c4 = (const float4*)cb;
  ushort4* s4 = (ushort4*)cs;
#pragma unroll
  for (int k = 0; k < 4; ++k) {
    int i = gid + k * 131072;                        // < 524288
    float4 v = c4[i];
    s4[i] = make_ushort4(f2bf(v.x), f2bf(v.y), f2bf(v.z), f2bf(v.w));
  }
}

// per-row init for q=0: Anorm(z), Rsplit=bf16(z), wsmin/choice/cnt init
__global__ void rvq_init_rows(const float* __restrict__ z, float* __restrict__ ws) {
  int t = blockIdx.x * blockDim.x + threadIdx.x;     // 32768 threads
  ws[WS_ANORM + t] = sum256_sq_np(z + (size_t)t * DN);
  ((unsigned int*)(ws + WS_MIN))[t] = 0x7f7fffffu;
  ((unsigned long long*)(ws + WS_CHOICE))[t] = ~0ull;
  if (t == 0) ((unsigned int*)(ws + WS_CNT))[0] = 0u;
  const float4* z4 = (const float4*)z;
  ushort4* r4 = (ushort4*)(ws + WS_RSPLIT);
#pragma unroll 8
  for (int i = 0; i < 64; ++i) {
    int idx = i * 32768 + t;
    float4 v = z4[idx];
    r4[idx] = make_ushort4(f2bf(v.x), f2bf(v.y), f2bf(v.z), f2bf(v.w));
  }
}

// bf16 screening GEMM + per-row block-min + candidate append.
// 128x128 tile, 16x16x32 MFMA, XOR-swizzled LDS (conflict-free b128 frags).
__global__ __launch_bounds__(256, 3) void rvq_screen(const float* __restrict__ ws_ro,
                                                     float* __restrict__ ws, int q) {
  __shared__ __align__(16) unsigned short As[128 * 64];
  __shared__ __align__(16) unsigned short Bs[128 * 64];
  __shared__ float rD[2][128];
  __shared__ float an_s[128], cn_s[128];

  const int tid = threadIdx.x;
  const int row0 = (blockIdx.x >> 3) * 128;
  const int col0 = (blockIdx.x & 7) * 128;
  const int wv = tid >> 6, lane = tid & 63, quad = lane >> 4, l15 = lane & 15;

  const uint4* Ag = (const uint4*)(ws_ro + WS_RSPLIT);                       // row stride 32 uint4
  const uint4* Bg = (const uint4*)((const unsigned short*)(ws_ro + WS_CSPLIT) + (size_t)q * KN * DN);

  f32x4 acc[4][4];
#pragma unroll
  for (int i = 0; i < 4; ++i)
#pragma unroll
    for (int j = 0; j < 4; ++j) acc[i][j] = (f32x4){0.f, 0.f, 0.f, 0.f};

  const int rb = tid >> 3, cch = tid & 7;
  for (int kk = 0; kk < 4; ++kk) {
    __syncthreads();
#pragma unroll
    for (int p = 0; p < 4; ++p) {
      int r = p * 32 + rb;
      uint4 av = Ag[(size_t)(row0 + r) * 32 + kk * 8 + cch];
      uint4 bv = Bg[(size_t)(col0 + r) * 32 + kk * 8 + cch];
      int cp = cch ^ (r & 7);
      ((uint4*)As)[r * 8 + cp] = av;
      ((uint4*)Bs)[r * 8 + cp] = bv;
    }
    __syncthreads();
#pragma unroll
    for (int s = 0; s < 2; ++s) {
      short8v a[4], b[4];
      int ph = (s * 4 + quad) ^ (l15 & 7);   // row&7 == l15&7 for both tiles
#pragma unroll
      for (int i = 0; i < 4; ++i) {
        int ra = (wv >> 1) * 64 + i * 16 + l15;
        int rc = (wv & 1) * 64 + i * 16 + l15;
        a[i] = *(const short8v*)&As[ra * 64 + ph * 8];
        b[i] = *(const short8v*)&Bs[rc * 64 + ph * 8];
      }
#pragma unroll
      for (int i = 0; i < 4; ++i)
#pragma unroll
        for (int j = 0; j < 4; ++j)
          acc[i][j] = __builtin_amdgcn_mfma_f32_16x16x32_bf16(a[i], b[j], acc[i][j], 0, 0, 0);
    }
  }
  __syncthreads();
  if (tid < 128) {
    an_s[tid] = ws_ro[WS_ANORM + row0 + tid];
    cn_s[tid] = ws_ro[WS_CNORM + q * KN + col0 + tid];
  }
  __syncthreads();

  // per-(i,reg) row minima over this wave's 64 cols
#pragma unroll
  for (int i = 0; i < 4; ++i) {
#pragma unroll
    for (int reg = 0; reg < 4; ++reg) {
      int rl = (wv >> 1) * 64 + i * 16 + quad * 4 + reg;
      float an = an_s[rl];
      float bd = 3.402823466e+38f;
#pragma unroll
      for (int j = 0; j < 4; ++j) {
        int cl = (wv & 1) * 64 + j * 16 + l15;
        float d = __fadd_rn(__fadd_rn(an, -2.0f * acc[i][j][reg]), cn_s[cl]);
        bd = (d < bd) ? d : bd;
      }
#pragma unroll
      for (int m = 1; m <= 8; m <<= 1) {
        float od = __shfl_xor(bd, m, 64);
        bd = (od < bd) ? od : bd;
      }
      if (l15 == 0) rD[wv & 1][rl] = bd;
    }
  }
  __syncthreads();
  if (tid < 128) {
    float m0 = rD[0][tid], m1 = rD[1][tid];
    float bm = (m1 < m0) ? m1 : m0;
    rD[0][tid] = bm;
    atomicMin((unsigned int*)(ws + WS_MIN) + row0 + tid, __float_as_uint(bm));
  }
  __syncthreads();

  // append candidates: d <= blockmin(row) + MARGIN  (superset of global-min window)
  unsigned int* cnt = (unsigned int*)(ws + WS_CNT);
  uint2* cand = (uint2*)(ws + WS_CAND);
#pragma unroll
  for (int i = 0; i < 4; ++i) {
#pragma unroll
    for (int reg = 0; reg < 4; ++reg) {
      int rl = (wv >> 1) * 64 + i * 16 + quad * 4 + reg;
      float an = an_s[rl];
      float thr = rD[0][rl] + MARGIN;
#pragma unroll
      for (int j = 0; j < 4; ++j) {
        int cl = (wv & 1) * 64 + j * 16 + l15;
        float d = __fadd_rn(__fadd_rn(an, -2.0f * acc[i][j][reg]), cn_s[cl]);
        if (d <= thr) {
          unsigned int pos = atomicAdd(cnt, 1u);
          if (pos < CAP)
            cand[pos] = make_uint2(__float_as_uint(d),
                                   ((unsigned)(row0 + rl) << 10) | (unsigned)(col0 + cl));
        }
      }
    }
  }
}

// exact recheck of survivors: round-1-validated serial fmaf chain, u64 atomicMin key
__global__ void rvq_recheck(const float* __restrict__ rsrc, const float* __restrict__ cb,
                            float* __restrict__ ws, int q) {
  const unsigned int* cntp = (const unsigned int*)(ws + WS_CNT);
  unsigned int n = *cntp;
  if (n > CAP) n = CAP;
  const uint2* cand = (const uint2*)(ws + WS_CAND);
  const unsigned int* wsmin = (const unsigned int*)(ws + WS_MIN);
  unsigned long long* choice = (unsigned long long*)(ws + WS_CHOICE);
  const float* cbq = cb + (size_t)q * KN * DN;
  const float* cnq = ws + WS_CNORM + q * KN;
  int stride = gridDim.x * blockDim.x;
  for (unsigned int e = blockIdx.x * blockDim.x + threadIdx.x; e < n; e += stride) {
    uint2 en = cand[e];
    float ds = __uint_as_float(en.x);
    int row = en.y >> 10, code = en.y & 1023;
    float thr = __uint_as_float(wsmin[row]) + MARGIN;
    if (ds > thr) continue;
    const float* r = rsrc + (size_t)row * DN;
    const float* c = cbq + (size_t)code * DN;
    float B = 0.f;
#pragma unroll 16
    for (int d = 0; d < DN; ++d) B = fmaf(r[d], c[d], B);   // sequential, matches round 1
    float de = __fadd_rn(__fadd_rn(ws[WS_ANORM + row], -2.0f * B), cnq[code]);
    unsigned long long key = ((unsigned long long)__float_as_uint(de) << 32) | (unsigned)code;
    atomicMin(choice + row, key);
  }
}

// np-exact residual/loss update; emits next-q Rsplit/Anorm + resets; last q writes out0
__global__ void rvq_update(const float* __restrict__ rsrc, const float* __restrict__ z,
                           const float* __restrict__ cb, float* __restrict__ ws,
                           float* __restrict__ out, int q) {
  __shared__ float lr[32][264];
  const int tid = threadIdx.x;
  const int urow = tid >> 3, udg = tid & 7;
  const int row = blockIdx.x * 32 + urow;
  const unsigned long long* choice = (const unsigned long long*)(ws + WS_CHOICE);
  const int idx = (int)(choice[row] & 1023u);
  if (udg == 0) out[IDX_BASE + (size_t)q * NROWS + row] = (float)idx;

  const float4* r4 = (const float4*)(rsrc + (size_t)row * DN) + udg * 8;
  const float4* q4 = (const float4*)(cb + ((size_t)q * KN + idx) * DN) + udg * 8;
  const bool last = (q == QN - 1);
  float lp = 0.f;
  float4 rnb[8];
#pragma unroll
  for (int t = 0; t < 8; ++t) {
    float4 r = r4[t], qv = q4[t];
    float tx = __fadd_rn(qv.x, -r.x), ty = __fadd_rn(qv.y, -r.y);
    float tz = __fadd_rn(qv.z, -r.z), tw = __fadd_rn(qv.w, -r.w);
    float sx = __fadd_rn(r.x, tx), sy = __fadd_rn(r.y, ty);
    float sz = __fadd_rn(r.z, tz), sw = __fadd_rn(r.w, tw);
    rnb[t] = make_float4(__fadd_rn(r.x, -sx), __fadd_rn(r.y, -sy),
                         __fadd_rn(r.z, -sz), __fadd_rn(r.w, -sw));
    lp = fmaf(tx, tx, lp); lp = fmaf(ty, ty, lp);
    lp = fmaf(tz, tz, lp); lp = fmaf(tw, tw, lp);
  }

  if (last) {
    const float4* z4 = (const float4*)(z + (size_t)row * DN) + udg * 8;
    float4* o4 = (float4*)(out + (size_t)row * DN) + udg * 8;
#pragma unroll
    for (int t = 0; t < 8; ++t) {
      float4 zv = z4[t];
      o4[t] = make_float4(__fadd_rn(zv.x, -rnb[t].x), __fadd_rn(zv.y, -rnb[t].y),
                          __fadd_rn(zv.z, -rnb[t].z), __fadd_rn(zv.w, -rnb[t].w));
    }
  } else {
    float4* rd = (float4*)(ws + WS_RESID + (size_t)row * DN) + udg * 8;
    ushort4* rs = (ushort4*)((unsigned short*)(ws + WS_RSPLIT) + (size_t)row * DN) + udg * 8;
#pragma unroll
    for (int t = 0; t < 8; ++t) {
      float4 v = rnb[t];
      rd[t] = v;
      rs[t] = make_ushort4(f2bf(v.x), f2bf(v.y), f2bf(v.z), f2bf(v.w));
      *(float4*)&lr[urow][udg * 32 + t * 4] = v;
    }
  }

#pragma unroll
  for (int off = 32; off > 0; off >>= 1) lp += __shfl_down(lp, off, 64);
  if ((tid & 63) == 0) atomicAdd(ws + WS_LOSS + q, lp);

  if (!last) {
    __syncthreads();
    if (udg == 0) {
      ws[WS_ANORM + row] = sum256_sq_np(&lr[urow][0]);
      ((unsigned int*)(ws + WS_MIN))[row] = 0x7f7fffffu;
    }
    if (udg == 1) ((unsigned long long*)(ws + WS_CHOICE))[row] = ~0ull;
    if (tid == 0 && blockIdx.x == 0) ((unsigned int*)(ws + WS_CNT))[0] = 0u;
  }
}

__global__ void rvq_fin(const float* __restrict__ ws, float* __restrict__ out) {
  if (blockIdx.x == 0 && threadIdx.x == 0) {
    float vq = 0.f;
    for (int q = 0; q < QN; ++q) {
      float m = ws[WS_LOSS + q] / 8388608.0f;
      float l = __fadd_rn(m, 0.25f * m);
      vq = __fadd_rn(vq, l);
    }
    out[LOSS_OFF] = vq;
  }
}

extern "C" void kernel_launch(void* const* d_in, const int* in_sizes, int n_in,
                              void* d_out, int out_size, void* d_ws, size_t ws_size,
                              hipStream_t stream) {
  const float* z = (const float*)d_in[0];
  const float* cb = (const float*)d_in[1];
  float* out = (float*)d_out;
  float* ws = (float*)d_ws;

  hipLaunchKernelGGL(rvq_prep_norm, dim3(32), dim3(256), 0, stream, cb, ws);
  hipLaunchKernelGGL(rvq_prep_cast, dim3(512), dim3(256), 0, stream, cb,
                     (unsigned short*)(ws + WS_CSPLIT));
  hipLaunchKernelGGL(rvq_init_rows, dim3(128), dim3(256), 0, stream, z, ws);

  for (int q = 0; q < QN; ++q) {
    const float* rsrc = (q == 0) ? z : (const float*)(ws + WS_RESID);
    hipLaunchKernelGGL(rvq_screen, dim3(2048), dim3(256), 0, stream, ws, ws, q);
    hipLaunchKernelGGL(rvq_recheck, dim3(512), dim3(256), 0, stream, rsrc, cb, ws, q);
    hipLaunchKernelGGL(rvq_update, dim3(1024), dim3(256), 0, stream, rsrc, z, cb, ws, out, q);
  }
  hipLaunchKernelGGL(rvq_fin, dim3(1), dim3(64), 0, stream, ws, out);
}

// Round 3
// 1693.990 us; speedup vs baseline: 22.2859x; 22.2859x over previous
//
#include <hip/hip_runtime.h>

#define QN 8
#define KN 1024
#define DN 256
#define NROWS 32768
#define IDX_BASE 8388608
#define LOSS_OFF 8650752
#define MARGIN 8e-3f
#define CAP 2097152u
#define LCAP 2048u

// ws layout (float offsets)
#define WS_LOSS 0
#define WS_CNORM 8
#define WS_ANORM 8200
#define WS_MIN 40968
#define WS_CHOICE 73736      // u64[32768] -> 65536 floats
#define WS_CNT 139272
#define WS_CAND 139280       // uint2[CAP] -> 4194304 floats
#define WS_RESID 4333584     // float[8388608]
#define WS_RSPLIT 12722192   // bf16[8388608] -> 4194304 floats
#define WS_CSPLIT 16916496   // bf16[2097152] -> 1048576 floats

typedef __attribute__((ext_vector_type(8))) short short8v;
typedef __attribute__((ext_vector_type(4))) float f32x4;

static __device__ __forceinline__ unsigned short f2bf(float x) {
  unsigned int u = __float_as_uint(x);
  unsigned int r = (u + 0x7fffu + ((u >> 16) & 1u)) >> 16;
  return (unsigned short)r;
}

// numpy pairwise sum-of-squares over 256 floats (validated round 1: absmax 0.0)
__device__ __forceinline__ float sum256_sq_np(const float* p) {
  float h[2];
#pragma unroll
  for (int half = 0; half < 2; ++half) {
    const float* a = p + half * 128;
    float r[8];
#pragma unroll
    for (int j = 0; j < 8; ++j) r[j] = __fmul_rn(a[j], a[j]);
    for (int i = 8; i < 128; i += 8) {
#pragma unroll
      for (int j = 0; j < 8; ++j) r[j] = __fadd_rn(r[j], __fmul_rn(a[i + j], a[i + j]));
    }
    h[half] = __fadd_rn(__fadd_rn(__fadd_rn(r[0], r[1]), __fadd_rn(r[2], r[3])),
                        __fadd_rn(__fadd_rn(r[4], r[5]), __fadd_rn(r[6], r[7])));
  }
  return __fadd_rn(h[0], h[1]);
}

// cnorm (np-exact) + zero loss accumulators
__global__ void rvq_prep_norm(const float* __restrict__ cb, float* __restrict__ ws) {
  int g = blockIdx.x * blockDim.x + threadIdx.x;
  if (g < 8) ws[WS_LOSS + g] = 0.f;
  if (g < QN * KN) ws[WS_CNORM + g] = sum256_sq_np(cb + (size_t)g * DN);
}

// codebook -> bf16 (coalesced)
__global__ void rvq_prep_cast(const float* __restrict__ cb, unsigned short* __restrict__ cs) {
  int gid = blockIdx.x * blockDim.x + threadIdx.x;   // 131072 threads
  const float4* c4 = (const float4*)cb;
  ushort4* s4 = (ushort4*)cs;
#pragma unroll
  for (int k = 0; k < 4; ++k) {
    int i = gid + k * 131072;                        // < 524288
    float4 v = c4[i];
    s4[i] = make_ushort4(f2bf(v.x), f2bf(v.y), f2bf(v.z), f2bf(v.w));
  }
}

// per-row init for q=0: Anorm(z), Rsplit=bf16(z), wsmin/choice/cnt init
__global__ void rvq_init_rows(const float* __restrict__ z, float* __restrict__ ws) {
  int t = blockIdx.x * blockDim.x + threadIdx.x;     // 32768 threads
  ws[WS_ANORM + t] = sum256_sq_np(z + (size_t)t * DN);
  ((unsigned int*)(ws + WS_MIN))[t] = 0x7f7fffffu;
  ((unsigned long long*)(ws + WS_CHOICE))[t] = ~0ull;
  if (t == 0) ((unsigned int*)(ws + WS_CNT))[0] = 0u;
  const float4* z4 = (const float4*)z;
  ushort4* r4 = (ushort4*)(ws + WS_RSPLIT);
#pragma unroll 8
  for (int i = 0; i < 64; ++i) {
    int idx = i * 32768 + t;
    float4 v = z4[idx];
    r4[idx] = make_ushort4(f2bf(v.x), f2bf(v.y), f2bf(v.z), f2bf(v.w));
  }
}

// bf16 screening GEMM + per-row block-min + candidate append.
// 128x128 tile, 16x16x32 MFMA, XOR-swizzled LDS (conflict-free b128 frags).
// R3: candidate append via LDS staging + ONE global atomicAdd per block
// (R2 post-mortem: ~330K cross-XCD same-address atomics serialized the kernel)
__global__ __launch_bounds__(256, 3) void rvq_screen(const float* __restrict__ ws_ro,
                                                     float* __restrict__ ws, int q) {
  __shared__ __align__(16) unsigned short As[128 * 64];
  __shared__ __align__(16) unsigned short Bs[128 * 64];
  __shared__ float rD[2][128];
  __shared__ float an_s[128], cn_s[128];
  __shared__ uint2 lcand[LCAP];
  __shared__ unsigned int lcnt, lnum, lbase;

  const int tid = threadIdx.x;
  const int row0 = (blockIdx.x >> 3) * 128;
  const int col0 = (blockIdx.x & 7) * 128;
  const int wv = tid >> 6, lane = tid & 63, quad = lane >> 4, l15 = lane & 15;

  if (tid == 0) lcnt = 0u;   // synced by first kk-loop __syncthreads

  const uint4* Ag = (const uint4*)(ws_ro + WS_RSPLIT);                       // row stride 32 uint4
  const uint4* Bg = (const uint4*)((const unsigned short*)(ws_ro + WS_CSPLIT) + (size_t)q * KN * DN);

  f32x4 acc[4][4];
#pragma unroll
  for (int i = 0; i < 4; ++i)
#pragma unroll
    for (int j = 0; j < 4; ++j) acc[i][j] = (f32x4){0.f, 0.f, 0.f, 0.f};

  const int rb = tid >> 3, cch = tid & 7;
  for (int kk = 0; kk < 4; ++kk) {
    __syncthreads();
#pragma unroll
    for (int p = 0; p < 4; ++p) {
      int r = p * 32 + rb;
      uint4 av = Ag[(size_t)(row0 + r) * 32 + kk * 8 + cch];
      uint4 bv = Bg[(size_t)(col0 + r) * 32 + kk * 8 + cch];
      int cp = cch ^ (r & 7);
      ((uint4*)As)[r * 8 + cp] = av;
      ((uint4*)Bs)[r * 8 + cp] = bv;
    }
    __syncthreads();
#pragma unroll
    for (int s = 0; s < 2; ++s) {
      short8v a[4], b[4];
      int ph = (s * 4 + quad) ^ (l15 & 7);   // row&7 == l15&7 for both tiles
#pragma unroll
      for (int i = 0; i < 4; ++i) {
        int ra = (wv >> 1) * 64 + i * 16 + l15;
        int rc = (wv & 1) * 64 + i * 16 + l15;
        a[i] = *(const short8v*)&As[ra * 64 + ph * 8];
        b[i] = *(const short8v*)&Bs[rc * 64 + ph * 8];
      }
#pragma unroll
      for (int i = 0; i < 4; ++i)
#pragma unroll
        for (int j = 0; j < 4; ++j)
          acc[i][j] = __builtin_amdgcn_mfma_f32_16x16x32_bf16(a[i], b[j], acc[i][j], 0, 0, 0);
    }
  }
  __syncthreads();
  if (tid < 128) {
    an_s[tid] = ws_ro[WS_ANORM + row0 + tid];
    cn_s[tid] = ws_ro[WS_CNORM + q * KN + col0 + tid];
  }
  __syncthreads();

  // per-(i,reg) row minima over this wave's 64 cols
#pragma unroll
  for (int i = 0; i < 4; ++i) {
#pragma unroll
    for (int reg = 0; reg < 4; ++reg) {
      int rl = (wv >> 1) * 64 + i * 16 + quad * 4 + reg;
      float an = an_s[rl];
      float bd = 3.402823466e+38f;
#pragma unroll
      for (int j = 0; j < 4; ++j) {
        int cl = (wv & 1) * 64 + j * 16 + l15;
        float d = __fadd_rn(__fadd_rn(an, -2.0f * acc[i][j][reg]), cn_s[cl]);
        bd = (d < bd) ? d : bd;
      }
#pragma unroll
      for (int m = 1; m <= 8; m <<= 1) {
        float od = __shfl_xor(bd, m, 64);
        bd = (od < bd) ? od : bd;
      }
      if (l15 == 0) rD[wv & 1][rl] = bd;
    }
  }
  __syncthreads();
  if (tid < 128) {
    float m0 = rD[0][tid], m1 = rD[1][tid];
    float bm = (m1 < m0) ? m1 : m0;
    rD[0][tid] = bm;
    atomicMin((unsigned int*)(ws + WS_MIN) + row0 + tid, __float_as_uint(bm));
  }
  __syncthreads();

  // append candidates (d <= blockmin(row)+MARGIN) into LDS staging
  unsigned int* cnt = (unsigned int*)(ws + WS_CNT);
  uint2* cand = (uint2*)(ws + WS_CAND);
#pragma unroll
  for (int i = 0; i < 4; ++i) {
#pragma unroll
    for (int reg = 0; reg < 4; ++reg) {
      int rl = (wv >> 1) * 64 + i * 16 + quad * 4 + reg;
      float an = an_s[rl];
      float thr = rD[0][rl] + MARGIN;
#pragma unroll
      for (int j = 0; j < 4; ++j) {
        int cl = (wv & 1) * 64 + j * 16 + l15;
        float d = __fadd_rn(__fadd_rn(an, -2.0f * acc[i][j][reg]), cn_s[cl]);
        if (d <= thr) {
          uint2 e = make_uint2(__float_as_uint(d),
                               ((unsigned)(row0 + rl) << 10) | (unsigned)(col0 + cl));
          unsigned int p = atomicAdd(&lcnt, 1u);      // LDS atomic: cheap, within-CU
          if (p < LCAP) lcand[p] = e;
          else {                                      // overflow fallback (expected never)
            unsigned int gp = atomicAdd(cnt, 1u);
            if (gp < CAP) cand[gp] = e;
          }
        }
      }
    }
  }
  __syncthreads();
  if (tid == 0) {
    unsigned int n = lcnt; if (n > LCAP) n = LCAP;
    lnum = n;
    lbase = atomicAdd(cnt, n);                        // ONE global atomic per block
  }
  __syncthreads();
  for (unsigned int i = tid; i < lnum; i += 256u) {
    unsigned int gp = lbase + i;
    if (gp < CAP) cand[gp] = lcand[i];
  }
}

// exact recheck of survivors: round-1-validated serial fmaf chain, u64 atomicMin key
__global__ void rvq_recheck(const float* __restrict__ rsrc, const float* __restrict__ cb,
                            float* __restrict__ ws, int q) {
  const unsigned int* cntp = (const unsigned int*)(ws + WS_CNT);
  unsigned int n = *cntp;
  if (n > CAP) n = CAP;
  const uint2* cand = (const uint2*)(ws + WS_CAND);
  const unsigned int* wsmin = (const unsigned int*)(ws + WS_MIN);
  unsigned long long* choice = (unsigned long long*)(ws + WS_CHOICE);
  const float* cbq = cb + (size_t)q * KN * DN;
  const float* cnq = ws + WS_CNORM + q * KN;
  int stride = gridDim.x * blockDim.x;
  for (unsigned int e = blockIdx.x * blockDim.x + threadIdx.x; e < n; e += stride) {
    uint2 en = cand[e];
    float ds = __uint_as_float(en.x);
    int row = en.y >> 10, code = en.y & 1023;
    float thr = __uint_as_float(wsmin[row]) + MARGIN;
    if (ds > thr) continue;
    const float* r = rsrc + (size_t)row * DN;
    const float* c = cbq + (size_t)code * DN;
    float B = 0.f;
#pragma unroll 16
    for (int d = 0; d < DN; ++d) B = fmaf(r[d], c[d], B);   // sequential, matches round 1
    float de = __fadd_rn(__fadd_rn(ws[WS_ANORM + row], -2.0f * B), cnq[code]);
    unsigned long long key = ((unsigned long long)__float_as_uint(de) << 32) | (unsigned)code;
    atomicMin(choice + row, key);
  }
}

// np-exact residual/loss update; emits next-q Rsplit/Anorm + resets; last q writes out0
__global__ void rvq_update(const float* __restrict__ rsrc, const float* __restrict__ z,
                           const float* __restrict__ cb, float* __restrict__ ws,
                           float* __restrict__ out, int q) {
  __shared__ float lr[32][264];
  const int tid = threadIdx.x;
  const int urow = tid >> 3, udg = tid & 7;
  const int row = blockIdx.x * 32 + urow;
  const unsigned long long* choice = (const unsigned long long*)(ws + WS_CHOICE);
  const int idx = (int)(choice[row] & 1023u);
  if (udg == 0) out[IDX_BASE + (size_t)q * NROWS + row] = (float)idx;

  const float4* r4 = (const float4*)(rsrc + (size_t)row * DN) + udg * 8;
  const float4* q4 = (const float4*)(cb + ((size_t)q * KN + idx) * DN) + udg * 8;
  const bool last = (q == QN - 1);
  float lp = 0.f;
  float4 rnb[8];
#pragma unroll
  for (int t = 0; t < 8; ++t) {
    float4 r = r4[t], qv = q4[t];
    float tx = __fadd_rn(qv.x, -r.x), ty = __fadd_rn(qv.y, -r.y);
    float tz = __fadd_rn(qv.z, -r.z), tw = __fadd_rn(qv.w, -r.w);
    float sx = __fadd_rn(r.x, tx), sy = __fadd_rn(r.y, ty);
    float sz = __fadd_rn(r.z, tz), sw = __fadd_rn(r.w, tw);
    rnb[t] = make_float4(__fadd_rn(r.x, -sx), __fadd_rn(r.y, -sy),
                         __fadd_rn(r.z, -sz), __fadd_rn(r.w, -sw));
    lp = fmaf(tx, tx, lp); lp = fmaf(ty, ty, lp);
    lp = fmaf(tz, tz, lp); lp = fmaf(tw, tw, lp);
  }

  if (last) {
    const float4* z4 = (const float4*)(z + (size_t)row * DN) + udg * 8;
    float4* o4 = (float4*)(out + (size_t)row * DN) + udg * 8;
#pragma unroll
    for (int t = 0; t < 8; ++t) {
      float4 zv = z4[t];
      o4[t] = make_float4(__fadd_rn(zv.x, -rnb[t].x), __fadd_rn(zv.y, -rnb[t].y),
                          __fadd_rn(zv.z, -rnb[t].z), __fadd_rn(zv.w, -rnb[t].w));
    }
  } else {
    float4* rd = (float4*)(ws + WS_RESID + (size_t)row * DN) + udg * 8;
    ushort4* rs = (ushort4*)((unsigned short*)(ws + WS_RSPLIT) + (size_t)row * DN) + udg * 8;
#pragma unroll
    for (int t = 0; t < 8; ++t) {
      float4 v = rnb[t];
      rd[t] = v;
      rs[t] = make_ushort4(f2bf(v.x), f2bf(v.y), f2bf(v.z), f2bf(v.w));
      *(float4*)&lr[urow][udg * 32 + t * 4] = v;
    }
  }

#pragma unroll
  for (int off = 32; off > 0; off >>= 1) lp += __shfl_down(lp, off, 64);
  if ((tid & 63) == 0) atomicAdd(ws + WS_LOSS + q, lp);

  if (!last) {
    __syncthreads();
    if (udg == 0) {
      ws[WS_ANORM + row] = sum256_sq_np(&lr[urow][0]);
      ((unsigned int*)(ws + WS_MIN))[row] = 0x7f7fffffu;
    }
    if (udg == 1) ((unsigned long long*)(ws + WS_CHOICE))[row] = ~0ull;
    if (tid == 0 && blockIdx.x == 0) ((unsigned int*)(ws + WS_CNT))[0] = 0u;
  }
}

__global__ void rvq_fin(const float* __restrict__ ws, float* __restrict__ out) {
  if (blockIdx.x == 0 && threadIdx.x == 0) {
    float vq = 0.f;
    for (int q = 0; q < QN; ++q) {
      float m = ws[WS_LOSS + q] / 8388608.0f;
      float l = __fadd_rn(m, 0.25f * m);
      vq = __fadd_rn(vq, l);
    }
    out[LOSS_OFF] = vq;
  }
}

extern "C" void kernel_launch(void* const* d_in, const int* in_sizes, int n_in,
                              void* d_out, int out_size, void* d_ws, size_t ws_size,
                              hipStream_t stream) {
  const float* z = (const float*)d_in[0];
  const float* cb = (const float*)d_in[1];
  float* out = (float*)d_out;
  float* ws = (float*)d_ws;

  hipLaunchKernelGGL(rvq_prep_norm, dim3(32), dim3(256), 0, stream, cb, ws);
  hipLaunchKernelGGL(rvq_prep_cast, dim3(512), dim3(256), 0, stream, cb,
                     (unsigned short*)(ws + WS_CSPLIT));
  hipLaunchKernelGGL(rvq_init_rows, dim3(128), dim3(256), 0, stream, z, ws);

  for (int q = 0; q < QN; ++q) {
    const float* rsrc = (q == 0) ? z : (const float*)(ws + WS_RESID);
    hipLaunchKernelGGL(rvq_screen, dim3(2048), dim3(256), 0, stream, ws, ws, q);
    hipLaunchKernelGGL(rvq_recheck, dim3(512), dim3(256), 0, stream, rsrc, cb, ws, q);
    hipLaunchKernelGGL(rvq_update, dim3(1024), dim3(256), 0, stream, rsrc, z, cb, ws, out, q);
  }
  hipLaunchKernelGGL(rvq_fin, dim3(1), dim3(64), 0, stream, ws, out);
}